// Round 8
// baseline (940.172 us; speedup 1.0000x reference)
//
#include <hip/hip_runtime.h>

#define T_STEPS 512
#define INPUT   13
#define HIDDEN  64
#define MB      8     // batch rows per block -> grid 512 = 2 blocks/CU
#define CS      8     // timesteps per x-chunk
#define NCHUNK  (T_STEPS / CS)

typedef __attribute__((ext_vector_type(8))) short bf16x8;  // MFMA A/B frag (4 VGPR)
typedef __attribute__((ext_vector_type(4))) float f32x4;   // MFMA C/D frag

__device__ __forceinline__ float sigmoid_f(float x) {
    return 1.0f / (1.0f + __expf(-x));
}
__device__ __forceinline__ float tanh_f(float x) {
    return 1.0f - 2.0f / (1.0f + __expf(2.0f * x));
}
// float -> bf16 round-to-nearest-even (values are finite; no NaN handling)
__device__ __forceinline__ unsigned short f2bf(float f) {
    unsigned u = __float_as_uint(f);
    return (unsigned short)((u + 0x7FFFu + ((u >> 16) & 1u)) >> 16);
}
__device__ __forceinline__ float bf2f(unsigned short h) {
    return __uint_as_float(((unsigned)h) << 16);
}

// R7 post-mortem: MFMA kernel at 632us was LATENCY-bound: 1 block/CU =
// 1 wave/SIMD (Occupancy 11.7%), per-step wall 3300 cyc vs ~900 cyc of
// issue -> ~2/3 exposed latency (ds_read -> 9-deep MFMA chains -> trans
// chain -> ds_write -> barrier, nothing to overlap).
// R8: MB=8, grid 512 -> 2 blocks/CU (2 waves/SIMD): two independent
// recurrence streams per CU interleave. M-tile half-wasted (MFMA issue/CU
// doubles -- fine at 18% util). hA double-buffered -> ONE barrier/step.
// Rows 8-15 dropped from LDS: A-frag lanes 8-15 read row lr&7 (their D
// rows are dead); cell update exec-masked to lg<2. LDS 40KB -> 22KB.
__global__ __launch_bounds__(256, 2)
void lstm_mfma_kernel(const float* __restrict__ x,
                      const float* __restrict__ W_ih,
                      const float* __restrict__ W_hh,
                      const float* __restrict__ b_ih,
                      const float* __restrict__ b_hh,
                      const float* __restrict__ W_fc,
                      const float* __restrict__ b_fc,
                      float* __restrict__ out)
{
    // h frags: [buf][split][row(8)][k'(64)] bf16, XOR-swizzled slots
    // (slot ^= row) so b128 A-reads and b16 h-writes are conflict-free.
    __shared__ unsigned short hA[2][2][MB][HIDDEN];         // 4 KB
    // x frags: [buf][split][tt][row(8)][k'(32, zero-padded)], slot ^= row&3
    __shared__ unsigned short xA[2][2][CS][MB][32];         // 16 KB
    __shared__ float hf[MB][HIDDEN];                        // epilogue, 2 KB

    const int tid = threadIdx.x;
    const int w   = tid >> 6;      // wave 0..3
    const int l   = tid & 63;
    const int lr  = l & 15;        // MFMA row/col index
    const int lg  = l >> 4;        // MFMA k-group
    const int lr8 = lr & 7;        // clamped A-row (rows 8-15 are dead)
    const int row0 = blockIdx.x * MB;

    // ---- resident weight B-frags, built once ----
    // Wcat[g][k]: k<64 -> W_hh[g][k]; 64<=k<77 -> W_ih[g][k-64]; else 0.
    // B-frag elem j of (tile kf): B[k = kf*32 + lg*8 + j][col = lr],
    // col -> gate = 64*gt + 16*w + lr.
    bf16x8 Bf[4][3][2];
    float  bias[4];
    #pragma unroll
    for (int gt = 0; gt < 4; ++gt) {
        const int gate = gt * 64 + 16 * w + lr;
        bias[gt] = b_ih[gate] + b_hh[gate];
        #pragma unroll
        for (int kf = 0; kf < 3; ++kf) {
            bf16x8 bh, bl;
            #pragma unroll
            for (int j = 0; j < 8; ++j) {
                const int k = kf * 32 + lg * 8 + j;
                float v = 0.0f;
                if (k < 64)      v = W_hh[gate * HIDDEN + k];
                else if (k < 77) v = W_ih[gate * INPUT + (k - 64)];
                const unsigned short hi = f2bf(v);
                const unsigned short lo = f2bf(v - bf2f(hi));
                bh[j] = (short)hi;
                bl[j] = (short)lo;
            }
            Bf[gt][kf][0] = bh;
            Bf[gt][kf][1] = bl;
        }
    }

    // ---- zero LDS (h0 = 0; x pad slots stay 0 forever) ----
    for (int i = tid; i < 2 * 2 * MB * HIDDEN; i += 256)
        ((unsigned short*)hA)[i] = 0;
    for (int i = tid; i < 2 * 2 * CS * MB * 32; i += 256)
        ((unsigned short*)xA)[i] = 0;

    float c[4]    = {0.f, 0.f, 0.f, 0.f};
    float hreg[4] = {0.f, 0.f, 0.f, 0.f};
    const bool upd = (lg < 2);     // lanes owning live D rows 0..7

    // ---- x chunk loader: 8 rows x 8 tt x 16 (padded) = 1024 slots ----
    float stg[4];
    auto load_chunk = [&](int ch) {
        #pragma unroll
        for (int s = 0; s < 4; ++s) {
            const int idx = tid + s * 256;   // 0..1023
            const int i   = idx & 15;
            const int tt  = (idx >> 4) & 7;
            const int r   = idx >> 7;        // 0..7
            float v = 0.0f;
            if (i < INPUT)
                v = x[(size_t)(row0 + r) * (T_STEPS * INPUT)
                      + (size_t)(ch * CS + tt) * INPUT + i];
            stg[s] = v;
        }
    };
    auto store_chunk = [&](int buf) {
        #pragma unroll
        for (int s = 0; s < 4; ++s) {
            const int idx = tid + s * 256;
            const int i   = idx & 15;
            const int tt  = (idx >> 4) & 7;
            const int r   = idx >> 7;
            const unsigned short hi = f2bf(stg[s]);
            const unsigned short lo = f2bf(stg[s] - bf2f(hi));
            const int kp = (i & 7) | (((i >> 3) ^ (r & 3)) << 3);
            xA[buf][0][tt][r][kp] = hi;
            xA[buf][1][tt][r][kp] = lo;
        }
    };

    load_chunk(0);
    __syncthreads();          // zero-init visible
    store_chunk(0);
    __syncthreads();

    for (int ch = 0; ch < NCHUNK; ++ch) {
        const int cur = ch & 1;
        if (ch + 1 < NCHUNK)
            load_chunk(ch + 1);          // global loads in flight over 8 steps

        #pragma unroll 1
        for (int tt = 0; tt < CS; ++tt) {
            const int hb = tt & 1;       // CS even -> parity consistent

            // ---- A-frag reads (rows 8-15 duplicate row lr&7; dead D rows) ----
            bf16x8 ah[2][2];   // [split][kf]
            #pragma unroll
            for (int sp = 0; sp < 2; ++sp)
                #pragma unroll
                for (int kf = 0; kf < 2; ++kf) {
                    const int slot = (kf * 4 + lg) ^ lr8;
                    ah[sp][kf] = *(const bf16x8*)((const char*)&hA[hb][sp][lr8][0] + slot * 16);
                }
            bf16x8 ax[2];
            #pragma unroll
            for (int sp = 0; sp < 2; ++sp) {
                const int slot = lg ^ (lr8 & 3);
                ax[sp] = *(const bf16x8*)((const char*)&xA[cur][sp][tt][lr8][0] + slot * 16);
            }

            // ---- gate GEMM: 9 MFMAs per gate-type (hh x2kf, hl x2kf, lh x2kf, x-terms x3) ----
            f32x4 acc[4];
            #pragma unroll
            for (int gt = 0; gt < 4; ++gt) {
                f32x4 a = {bias[gt], bias[gt], bias[gt], bias[gt]};
                #pragma unroll
                for (int kf = 0; kf < 2; ++kf) {
                    a = __builtin_amdgcn_mfma_f32_16x16x32_bf16(ah[0][kf], Bf[gt][kf][0], a, 0, 0, 0);
                    a = __builtin_amdgcn_mfma_f32_16x16x32_bf16(ah[0][kf], Bf[gt][kf][1], a, 0, 0, 0);
                    a = __builtin_amdgcn_mfma_f32_16x16x32_bf16(ah[1][kf], Bf[gt][kf][0], a, 0, 0, 0);
                }
                a = __builtin_amdgcn_mfma_f32_16x16x32_bf16(ax[0], Bf[gt][2][0], a, 0, 0, 0);
                a = __builtin_amdgcn_mfma_f32_16x16x32_bf16(ax[0], Bf[gt][2][1], a, 0, 0, 0);
                a = __builtin_amdgcn_mfma_f32_16x16x32_bf16(ax[1], Bf[gt][2][0], a, 0, 0, 0);
                acc[gt] = a;
            }

            // ---- cell update (rows 0..7 live in lg<2); write split h ----
            if (upd) {
                #pragma unroll
                for (int r = 0; r < 4; ++r) {
                    const float ig = sigmoid_f(acc[0][r]);
                    const float fg = sigmoid_f(acc[1][r]);
                    const float gg = tanh_f   (acc[2][r]);
                    const float og = sigmoid_f(acc[3][r]);
                    c[r] = fg * c[r] + ig * gg;
                    const float h = og * tanh_f(c[r]);
                    hreg[r] = h;
                    const unsigned short hi = f2bf(h);
                    const unsigned short lo = f2bf(h - bf2f(hi));
                    const int row = lg * 4 + r;          // 0..7
                    const int k   = 16 * w + lr;
                    const int kp  = (k & 7) | (((k >> 3) ^ row) << 3);
                    hA[hb ^ 1][0][row][kp] = hi;
                    hA[hb ^ 1][1][row][kp] = lo;
                }
            }
            __syncthreads();   // writes to hA[hb^1] visible; guards next reads
        }

        if (ch + 1 < NCHUNK) {
            store_chunk(1 - cur);        // waits on the global loads above
            __syncthreads();
        }
    }

    // ---- epilogue: out[row] = sigmoid(h_T . W_fc + b_fc) ----
    if (upd) {
        #pragma unroll
        for (int r = 0; r < 4; ++r)
            hf[lg * 4 + r][16 * w + lr] = hreg[r];
    }
    __syncthreads();
    if (tid < MB) {
        float a = b_fc[0];
        #pragma unroll
        for (int j = 0; j < HIDDEN; ++j)
            a = fmaf(hf[tid][j], W_fc[j], a);
        out[row0 + tid] = sigmoid_f(a);
    }
}

extern "C" void kernel_launch(void* const* d_in, const int* in_sizes, int n_in,
                              void* d_out, int out_size, void* d_ws, size_t ws_size,
                              hipStream_t stream) {
    const float* x    = (const float*)d_in[0];
    const float* W_ih = (const float*)d_in[1];
    const float* W_hh = (const float*)d_in[2];
    const float* b_ih = (const float*)d_in[3];
    const float* b_hh = (const float*)d_in[4];
    const float* W_fc = (const float*)d_in[5];
    const float* b_fc = (const float*)d_in[6];
    float* out = (float*)d_out;

    const int B = 4096;
    dim3 grid(B / MB), block(256);
    lstm_mfma_kernel<<<grid, block, 0, stream>>>(x, W_ih, W_hh, b_ih, b_hh,
                                                 W_fc, b_fc, out);
}

// Round 9
// 577.260 us; speedup vs baseline: 1.6287x; 1.6287x over previous
//
#include <hip/hip_runtime.h>

#define T_STEPS 512
#define INPUT   13
#define HIDDEN  64
#define MB      16    // full MFMA M-tile, grid 256 = 1 block/CU (R8 showed MB=8 loses)
#define CS      8     // timesteps per x-chunk
#define NCHUNK  (T_STEPS / CS)

typedef __attribute__((ext_vector_type(8))) _Float16 f16x8;  // MFMA A/B frag (4 VGPR)
typedef __attribute__((ext_vector_type(4)))  float   f32x4;  // MFMA C/D frag

__device__ __forceinline__ float sigmoid_f(float x) {
    return 1.0f / (1.0f + __expf(-x));
}
__device__ __forceinline__ float tanh_f(float x) {
    return 1.0f - 2.0f / (1.0f + __expf(2.0f * x));
}

// R8 post-mortem: MB=8/2-blocks lost (issue doubled > latency hidden). Keep
// R7 shape (MB=16, 1 block/CU) and shrink the step critical path:
//  - f16 2-term split (h = hi+lo, W single f16): f16 products are exact in
//    the f32 accumulator, so only W's one-time f16 quantization (~6e-5)
//    remains. 24 MFMAs/step (was 36), B-frags 48 VGPR (was 96).
//  - per-gate chain split into 2 accs of depth 3 (was 9-deep serial).
//  - double-buffered hA (from R8) -> ONE barrier per step (was 2).
__global__ __launch_bounds__(256, 1)
void lstm_mfma_kernel(const float* __restrict__ x,
                      const float* __restrict__ W_ih,
                      const float* __restrict__ W_hh,
                      const float* __restrict__ b_ih,
                      const float* __restrict__ b_hh,
                      const float* __restrict__ W_fc,
                      const float* __restrict__ b_fc,
                      float* __restrict__ out)
{
    // h frags: [buf][split][row][k] f16, slot ^= row&7 swizzle (slot = 16B)
    __shared__ _Float16 hA[2][2][MB][HIDDEN];      // 8 KB
    // x frags: [buf][split][tt][row][k(32, zero-padded)], slot ^= row&3
    __shared__ _Float16 xA[2][2][CS][MB][32];      // 32 KB
    __shared__ float hf[MB][HIDDEN];               // epilogue, 4 KB

    const int tid = threadIdx.x;
    const int w   = tid >> 6;      // wave 0..3
    const int l   = tid & 63;
    const int lr  = l & 15;        // MFMA row/col index
    const int lg  = l >> 4;        // MFMA k-group
    const int row0 = blockIdx.x * MB;

    // ---- resident weight B-frags (single f16 -- no lo split needed) ----
    // B[k][col]: col -> gate = 64*gt + 16*w + lr; elem j -> k = kf*32 + lg*8 + j.
    // Bh: K 0..63 = W_hh columns; Bx: K 0..31 of x-space (0..12 real).
    f16x8 Bh[4][2], Bx[4];
    float bias[4];
    #pragma unroll
    for (int gt = 0; gt < 4; ++gt) {
        const int gate = gt * 64 + 16 * w + lr;
        bias[gt] = b_ih[gate] + b_hh[gate];
        #pragma unroll
        for (int kf = 0; kf < 2; ++kf)
            #pragma unroll
            for (int j = 0; j < 8; ++j)
                Bh[gt][kf][j] = (_Float16)W_hh[gate * HIDDEN + kf * 32 + lg * 8 + j];
        #pragma unroll
        for (int j = 0; j < 8; ++j) {
            const int k = lg * 8 + j;
            Bx[gt][j] = (_Float16)((k < INPUT) ? W_ih[gate * INPUT + k] : 0.0f);
        }
    }

    // ---- zero LDS (h0 = 0; x pad slots stay 0 forever) ----
    for (int i = tid; i < 2 * 2 * MB * HIDDEN; i += 256)
        ((unsigned short*)hA)[i] = 0;
    for (int i = tid; i < 2 * 2 * CS * MB * 32; i += 256)
        ((unsigned short*)xA)[i] = 0;

    float c[4]    = {0.f, 0.f, 0.f, 0.f};
    float hreg[4] = {0.f, 0.f, 0.f, 0.f};

    // ---- x chunk loader: 16 rows x 8 tt x 16 (padded) = 2048 slots ----
    float stg[8];
    auto load_chunk = [&](int ch) {
        #pragma unroll
        for (int s = 0; s < 8; ++s) {
            const int idx = tid + s * 256;   // 0..2047
            const int i   = idx & 15;
            const int tt  = (idx >> 4) & 7;
            const int r   = idx >> 7;        // 0..15
            float v = 0.0f;
            if (i < INPUT)
                v = x[(size_t)(row0 + r) * (T_STEPS * INPUT)
                      + (size_t)(ch * CS + tt) * INPUT + i];
            stg[s] = v;
        }
    };
    auto store_chunk = [&](int buf) {
        #pragma unroll
        for (int s = 0; s < 8; ++s) {
            const int idx = tid + s * 256;
            const int i   = idx & 15;
            const int tt  = (idx >> 4) & 7;
            const int r   = idx >> 7;
            const _Float16 hi = (_Float16)stg[s];
            const _Float16 lo = (_Float16)(stg[s] - (float)hi);
            const int kp = (i & 7) | (((i >> 3) ^ (r & 3)) << 3);
            xA[buf][0][tt][r][kp] = hi;
            xA[buf][1][tt][r][kp] = lo;
        }
    };

    load_chunk(0);
    __syncthreads();          // zero-init visible
    store_chunk(0);
    __syncthreads();

    for (int ch = 0; ch < NCHUNK; ++ch) {
        const int cur = ch & 1;
        if (ch + 1 < NCHUNK)
            load_chunk(ch + 1);          // global loads in flight over 8 steps

        #pragma unroll 1
        for (int tt = 0; tt < CS; ++tt) {
            const int hb = tt & 1;       // CS even -> parity consistent

            // ---- A-frag reads: row = lr, slot (conceptual k/8) ^ swizzle ----
            f16x8 ah[2][2];   // [split][kf]
            #pragma unroll
            for (int sp = 0; sp < 2; ++sp)
                #pragma unroll
                for (int kf = 0; kf < 2; ++kf) {
                    const int slot = (kf * 4 + lg) ^ (lr & 7);
                    ah[sp][kf] = *(const f16x8*)((const char*)&hA[hb][sp][lr][0] + slot * 16);
                }
            f16x8 ax[2];
            #pragma unroll
            for (int sp = 0; sp < 2; ++sp) {
                const int slot = lg ^ (lr & 3);
                ax[sp] = *(const f16x8*)((const char*)&xA[cur][sp][tt][lr][0] + slot * 16);
            }

            // ---- gate GEMM: 6 MFMAs/gate-type in 2 chains of depth 3 ----
            f32x4 acc[4];
            #pragma unroll
            for (int gt = 0; gt < 4; ++gt) {
                f32x4 aA = {bias[gt], bias[gt], bias[gt], bias[gt]};
                aA = __builtin_amdgcn_mfma_f32_16x16x32_f16(ah[0][0], Bh[gt][0], aA, 0, 0, 0);
                aA = __builtin_amdgcn_mfma_f32_16x16x32_f16(ah[1][0], Bh[gt][0], aA, 0, 0, 0);
                aA = __builtin_amdgcn_mfma_f32_16x16x32_f16(ax[0],    Bx[gt],    aA, 0, 0, 0);
                f32x4 aB = {0.f, 0.f, 0.f, 0.f};
                aB = __builtin_amdgcn_mfma_f32_16x16x32_f16(ah[0][1], Bh[gt][1], aB, 0, 0, 0);
                aB = __builtin_amdgcn_mfma_f32_16x16x32_f16(ah[1][1], Bh[gt][1], aB, 0, 0, 0);
                aB = __builtin_amdgcn_mfma_f32_16x16x32_f16(ax[1],    Bx[gt],    aB, 0, 0, 0);
                acc[gt] = aA + aB;
            }

            // ---- in-register cell update; write split h to other buffer ----
            // D layout: row = lg*4 + r, col(cell) = 16w + lr
            #pragma unroll
            for (int r = 0; r < 4; ++r) {
                const float ig = sigmoid_f(acc[0][r]);
                const float fg = sigmoid_f(acc[1][r]);
                const float gg = tanh_f   (acc[2][r]);
                const float og = sigmoid_f(acc[3][r]);
                c[r] = fg * c[r] + ig * gg;
                const float h = og * tanh_f(c[r]);
                hreg[r] = h;
                const _Float16 hi = (_Float16)h;
                const _Float16 lo = (_Float16)(h - (float)hi);
                const int row = lg * 4 + r;
                const int k   = 16 * w + lr;
                const int kp  = (k & 7) | (((k >> 3) ^ (row & 7)) << 3);
                hA[hb ^ 1][0][row][kp] = hi;
                hA[hb ^ 1][1][row][kp] = lo;
            }
            __syncthreads();   // one barrier/step: dbuf makes read/write disjoint
        }

        if (ch + 1 < NCHUNK) {
            store_chunk(1 - cur);        // waits on the global loads above
            __syncthreads();
        }
    }

    // ---- epilogue: out[row] = sigmoid(h_T . W_fc + b_fc) ----
    #pragma unroll
    for (int r = 0; r < 4; ++r)
        hf[lg * 4 + r][16 * w + lr] = hreg[r];
    __syncthreads();
    if (tid < MB) {
        float a = b_fc[0];
        #pragma unroll
        for (int j = 0; j < HIDDEN; ++j)
            a = fmaf(hf[tid][j], W_fc[j], a);
        out[row0 + tid] = sigmoid_f(a);
    }
}

extern "C" void kernel_launch(void* const* d_in, const int* in_sizes, int n_in,
                              void* d_out, int out_size, void* d_ws, size_t ws_size,
                              hipStream_t stream) {
    const float* x    = (const float*)d_in[0];
    const float* W_ih = (const float*)d_in[1];
    const float* W_hh = (const float*)d_in[2];
    const float* b_ih = (const float*)d_in[3];
    const float* b_hh = (const float*)d_in[4];
    const float* W_fc = (const float*)d_in[5];
    const float* b_fc = (const float*)d_in[6];
    float* out = (float*)d_out;

    const int B = 4096;
    dim3 grid(B / MB), block(256);
    lstm_mfma_kernel<<<grid, block, 0, stream>>>(x, W_ih, W_hh, b_ih, b_hh,
                                                 W_fc, b_fc, out);
}

// Round 10
// 351.244 us; speedup vs baseline: 2.6767x; 1.6435x over previous
//
#include <hip/hip_runtime.h>

#define T_STEPS 512
#define INPUT   13
#define HIDDEN  64
#define MB      16    // full MFMA M-tile, grid 256 = 1 block/CU
#define CS      8     // timesteps per x-chunk
#define NCHUNK  (T_STEPS / CS)

typedef __attribute__((ext_vector_type(8))) _Float16 f16x8;  // MFMA A/B frag (4 VGPR)
typedef __attribute__((ext_vector_type(4)))  float   f32x4;  // MFMA C/D frag

// RAW v_rcp_f32 (~1 ulp) instead of IEEE f32 division: without -ffast-math,
// "1.0f/x" emits the full div_scale/div_fmas/div_fixup sequence (~8-10 ops,
// quarter-rate) -- at 20 divisions/lane/step this was ~500-800 cyc of the
// measured 1900-cyc VALUBusy wall. Activation accuracy impact: ~1e-7.
__device__ __forceinline__ float fast_rcp(float x) {
    return __builtin_amdgcn_rcpf(x);
}
__device__ __forceinline__ float sigmoid_f(float x) {
    return fast_rcp(1.0f + __expf(-x));
}
__device__ __forceinline__ float tanh_f(float x) {
    return 1.0f - 2.0f * fast_rcp(1.0f + __expf(2.0f * x));
}

// R9 post-mortem: issue-bound on VALU (63% VALUBusy = ~1900 cyc/step/SIMD vs
// ~700 from source math). Culprits: IEEE f32 division in activations (fixed
// via rcp), in-loop swizzled-address recomputation, rolled tt loop. R10:
// same math/structure as R9 (f16 2-term split, 24 MFMA/step/wave), but all
// LDS pointers precomputed, 8-step body fully unrolled (LDS ops = base+imm),
// bias as MFMA C-operand, x-MFMAs first, chunk barrier folded into step 8.
__global__ __launch_bounds__(256, 1)
void lstm_mfma_kernel(const float* __restrict__ x,
                      const float* __restrict__ W_ih,
                      const float* __restrict__ W_hh,
                      const float* __restrict__ b_ih,
                      const float* __restrict__ b_hh,
                      const float* __restrict__ W_fc,
                      const float* __restrict__ b_fc,
                      float* __restrict__ out)
{
    // h frags: [buf][split][row][k] f16, slot ^= row&7 swizzle (slot = 16B)
    __shared__ _Float16 hA[2][2][MB][HIDDEN];      // 8 KB
    // x frags: [buf][split][tt][row][k(32, zero-padded)], slot ^= row&3
    __shared__ _Float16 xA[2][2][CS][MB][32];      // 32 KB
    __shared__ float hf[MB][HIDDEN];               // epilogue, 4 KB

    const int tid = threadIdx.x;
    const int w   = tid >> 6;      // wave 0..3
    const int l   = tid & 63;
    const int lr  = l & 15;        // MFMA row/col index
    const int lg  = l >> 4;        // MFMA k-group
    const int row0 = blockIdx.x * MB;

    // ---- resident weight B-frags (single f16) + bias as f32x4 C-operand ----
    f16x8 Bh[4][2], Bx[4];
    f32x4 biasv[4];
    #pragma unroll
    for (int gt = 0; gt < 4; ++gt) {
        const int gate = gt * 64 + 16 * w + lr;
        const float b = b_ih[gate] + b_hh[gate];
        biasv[gt] = (f32x4){b, b, b, b};
        #pragma unroll
        for (int kf = 0; kf < 2; ++kf)
            #pragma unroll
            for (int j = 0; j < 8; ++j)
                Bh[gt][kf][j] = (_Float16)W_hh[gate * HIDDEN + kf * 32 + lg * 8 + j];
        #pragma unroll
        for (int j = 0; j < 8; ++j) {
            const int k = lg * 8 + j;
            Bx[gt][j] = (_Float16)((k < INPUT) ? W_ih[gate * INPUT + k] : 0.0f);
        }
    }

    // ---- precomputed LDS pointers (all thread-varying addressing hoisted) ----
    // h reads: frag (sp, kf) at parity hb = phr[hb][kf][sp*128]  (sp stride 2048B)
    const f16x8* phr[2][2];
    #pragma unroll
    for (int hb = 0; hb < 2; ++hb)
        #pragma unroll
        for (int kf = 0; kf < 2; ++kf) {
            const int slot = (kf * 4 + lg) ^ (lr & 7);
            phr[hb][kf] = (const f16x8*)((const char*)&hA[hb][0][lr][0] + slot * 16);
        }
    // x reads: px[cur*1024 + sp*512 + tt*64]  (f16x8 units)
    const int slx = lg ^ (lr & 3);
    const f16x8* px = (const f16x8*)((const char*)&xA[0][0][0][lr][0] + slx * 16);
    // h writes: pw[hb][r][0] = hi, pw[hb][r][1024] = lo  (sp stride 1024 u16)
    _Float16* pw[2][4];
    #pragma unroll
    for (int hb = 0; hb < 2; ++hb)
        #pragma unroll
        for (int r = 0; r < 4; ++r) {
            const int row = lg * 4 + r;
            const int k   = 16 * w + lr;
            const int kp  = (k & 7) | (((k >> 3) ^ (row & 7)) << 3);
            pw[hb][r] = &hA[hb][0][row][kp];
        }

    // ---- zero LDS (h0 = 0; x pad slots stay 0 forever) ----
    for (int i = tid; i < 2 * 2 * MB * HIDDEN; i += 256)
        ((unsigned short*)hA)[i] = 0;
    for (int i = tid; i < 2 * 2 * CS * MB * 32; i += 256)
        ((unsigned short*)xA)[i] = 0;

    float c[4]    = {0.f, 0.f, 0.f, 0.f};
    float hreg[4] = {0.f, 0.f, 0.f, 0.f};

    // ---- x chunk loader: 16 rows x 8 tt x 16 (padded) = 2048 slots ----
    float stg[8];
    auto load_chunk = [&](int ch) {
        #pragma unroll
        for (int s = 0; s < 8; ++s) {
            const int idx = tid + s * 256;   // 0..2047
            const int i   = idx & 15;
            const int tt  = (idx >> 4) & 7;
            const int r   = idx >> 7;        // 0..15
            float v = 0.0f;
            if (i < INPUT)
                v = x[(size_t)(row0 + r) * (T_STEPS * INPUT)
                      + (size_t)(ch * CS + tt) * INPUT + i];
            stg[s] = v;
        }
    };
    auto store_chunk = [&](int buf) {
        #pragma unroll
        for (int s = 0; s < 8; ++s) {
            const int idx = tid + s * 256;
            const int i   = idx & 15;
            const int tt  = (idx >> 4) & 7;
            const int r   = idx >> 7;
            const _Float16 hi = (_Float16)stg[s];
            const _Float16 lo = (_Float16)(stg[s] - (float)hi);
            const int kp = (i & 7) | (((i >> 3) ^ (r & 3)) << 3);
            xA[buf][0][tt][r][kp] = hi;
            xA[buf][1][tt][r][kp] = lo;
        }
    };

    load_chunk(0);
    __syncthreads();          // zero-init visible
    store_chunk(0);
    __syncthreads();

    for (int ch = 0; ch < NCHUNK; ++ch) {
        const int cur = ch & 1;
        const f16x8* pxc = px + cur * 1024;
        if (ch + 1 < NCHUNK)
            load_chunk(ch + 1);          // global loads in flight over 8 steps

        #pragma unroll
        for (int tt = 0; tt < CS; ++tt) {
            const int hb  = tt & 1;      // read parity (static after unroll)
            const int hbw = hb ^ 1;      // write parity

            // ---- LDS reads: x first, then h (all base+imm) ----
            const f16x8 ax0 = pxc[tt * 64];          // x hi
            const f16x8 ax1 = pxc[tt * 64 + 512];    // x lo
            const f16x8 ah_hi0 = phr[hb][0][0];
            const f16x8 ah_lo0 = phr[hb][0][128];
            const f16x8 ah_hi1 = phr[hb][1][0];
            const f16x8 ah_lo1 = phr[hb][1][128];

            // ---- gate GEMM: 6 MFMAs/gate-type, 2 chains of depth 3 ----
            f32x4 acc[4];
            #pragma unroll
            for (int gt = 0; gt < 4; ++gt) {
                f32x4 aA = biasv[gt];
                aA = __builtin_amdgcn_mfma_f32_16x16x32_f16(ax0,    Bx[gt],    aA, 0, 0, 0);
                aA = __builtin_amdgcn_mfma_f32_16x16x32_f16(ah_hi0, Bh[gt][0], aA, 0, 0, 0);
                aA = __builtin_amdgcn_mfma_f32_16x16x32_f16(ah_lo0, Bh[gt][0], aA, 0, 0, 0);
                f32x4 aB = {0.f, 0.f, 0.f, 0.f};
                aB = __builtin_amdgcn_mfma_f32_16x16x32_f16(ax1,    Bx[gt],    aB, 0, 0, 0);
                aB = __builtin_amdgcn_mfma_f32_16x16x32_f16(ah_hi1, Bh[gt][1], aB, 0, 0, 0);
                aB = __builtin_amdgcn_mfma_f32_16x16x32_f16(ah_lo1, Bh[gt][1], aB, 0, 0, 0);
                acc[gt] = aA + aB;
            }

            // ---- in-register cell update; write split h (base+imm) ----
            #pragma unroll
            for (int r = 0; r < 4; ++r) {
                const float ig = sigmoid_f(acc[0][r]);
                const float fg = sigmoid_f(acc[1][r]);
                const float gg = tanh_f   (acc[2][r]);
                const float og = sigmoid_f(acc[3][r]);
                c[r] = fg * c[r] + ig * gg;
                const float h = og * tanh_f(c[r]);
                hreg[r] = h;
                const _Float16 hi = (_Float16)h;
                const _Float16 lo = (_Float16)(h - (float)hi);
                pw[hbw][r][0]    = hi;
                pw[hbw][r][1024] = lo;     // split stride = MB*HIDDEN u16
            }

            // fold chunk staging into the last step (removes extra barrier)
            if (tt == CS - 1 && ch + 1 < NCHUNK)
                store_chunk(1 - cur);

            __syncthreads();
        }
    }

    // ---- epilogue: out[row] = sigmoid(h_T . W_fc + b_fc) ----
    #pragma unroll
    for (int r = 0; r < 4; ++r)
        hf[lg * 4 + r][16 * w + lr] = hreg[r];
    __syncthreads();
    if (tid < MB) {
        float a = b_fc[0];
        #pragma unroll
        for (int j = 0; j < HIDDEN; ++j)
            a = fmaf(hf[tid][j], W_fc[j], a);
        out[row0 + tid] = sigmoid_f(a);
    }
}

extern "C" void kernel_launch(void* const* d_in, const int* in_sizes, int n_in,
                              void* d_out, int out_size, void* d_ws, size_t ws_size,
                              hipStream_t stream) {
    const float* x    = (const float*)d_in[0];
    const float* W_ih = (const float*)d_in[1];
    const float* W_hh = (const float*)d_in[2];
    const float* b_ih = (const float*)d_in[3];
    const float* b_hh = (const float*)d_in[4];
    const float* W_fc = (const float*)d_in[5];
    const float* b_fc = (const float*)d_in[6];
    float* out = (float*)d_out;

    const int B = 4096;
    dim3 grid(B / MB), block(256);
    lstm_mfma_kernel<<<grid, block, 0, stream>>>(x, W_ih, W_hh, b_ih, b_hh,
                                                 W_fc, b_fc, out);
}

// Round 11
// 276.428 us; speedup vs baseline: 3.4011x; 1.2707x over previous
//
#include <hip/hip_runtime.h>

#define T_STEPS 512
#define INPUT   13
#define HIDDEN  64
#define MB      16    // full MFMA M-tile, grid 256 = 1 block/CU
#define CS      8     // timesteps per x-chunk
#define NCHUNK  (T_STEPS / CS)
#define LOG2E   1.44269504088896f

typedef __attribute__((ext_vector_type(8))) _Float16 f16x8;  // MFMA A/B frag (4 VGPR)
typedef __attribute__((ext_vector_type(4)))  float   f32x4;  // MFMA C/D frag

// Activation scales are FOLDED INTO THE WEIGHTS (R11):
//   sigma gates (i,f,o): acc = -log2e * pre  -> sigma = rcp(1 + exp2(acc))
//   g gate:              acc = 2*log2e * pre -> tanh  = 1 - 2*rcp(1 + exp2(acc))
// so each activation is exp2 + add + rcp (+fma for tanh), no per-step muls.
__device__ __forceinline__ float exp2_f(float x) { return __builtin_amdgcn_exp2f(x); }
__device__ __forceinline__ float rcp_f(float x)  { return __builtin_amdgcn_rcpf(x); }
__device__ __forceinline__ float sigmoid_f(float x) {           // epilogue only
    return rcp_f(1.0f + exp2_f(-LOG2E * x));
}

// R10 post-mortem: wall = serial sum of per-wave issue (1 wave/SIMD, cuts pay
// 1:1). R11 ledger cuts: drop x-lo MFMA term (24->20 MFMA; absmax evidence:
// bit-identical across precision schemes), fold activation scale/sign into
// W/b (exp2-direct activations), single 5-deep MFMA chain per gate (no
// second acc: kills 16 movs + 16 adds), xA single-plane (LDS 45->28 KB).
__global__ __launch_bounds__(256, 1)
void lstm_mfma_kernel(const float* __restrict__ x,
                      const float* __restrict__ W_ih,
                      const float* __restrict__ W_hh,
                      const float* __restrict__ b_ih,
                      const float* __restrict__ b_hh,
                      const float* __restrict__ W_fc,
                      const float* __restrict__ b_fc,
                      float* __restrict__ out)
{
    // h frags: [buf][split][row][k] f16, slot ^= row&7 swizzle (slot = 16B)
    __shared__ _Float16 hA[2][2][MB][HIDDEN];      // 8 KB
    // x frags: [buf][tt][row][k(32, zero-padded)] f16, slot ^= row&3
    __shared__ _Float16 xA[2][CS][MB][32];         // 16 KB
    __shared__ float hf[MB][HIDDEN];               // epilogue, 4 KB

    const int tid = threadIdx.x;
    const int w   = tid >> 6;      // wave 0..3
    const int l   = tid & 63;
    const int lr  = l & 15;        // MFMA row/col index
    const int lg  = l >> 4;        // MFMA k-group
    const int row0 = blockIdx.x * MB;

    // ---- resident weight B-frags (f16, activation-scale folded) ----
    f16x8 Bh[4][2], Bx[4];
    f32x4 biasv[4];
    #pragma unroll
    for (int gt = 0; gt < 4; ++gt) {
        const int gate  = gt * 64 + 16 * w + lr;
        const float scl = (gt == 2) ? (2.0f * LOG2E) : (-LOG2E);
        const float b   = scl * (b_ih[gate] + b_hh[gate]);
        biasv[gt] = (f32x4){b, b, b, b};
        #pragma unroll
        for (int kf = 0; kf < 2; ++kf)
            #pragma unroll
            for (int j = 0; j < 8; ++j)
                Bh[gt][kf][j] = (_Float16)(scl * W_hh[gate * HIDDEN + kf * 32 + lg * 8 + j]);
        #pragma unroll
        for (int j = 0; j < 8; ++j) {
            const int k = lg * 8 + j;
            Bx[gt][j] = (_Float16)((k < INPUT) ? scl * W_ih[gate * INPUT + k] : 0.0f);
        }
    }

    // ---- precomputed LDS pointers ----
    const f16x8* phr[2][2];        // h reads: [hb][kf], split at +128 (f16x8 units)
    #pragma unroll
    for (int hb = 0; hb < 2; ++hb)
        #pragma unroll
        for (int kf = 0; kf < 2; ++kf) {
            const int slot = (kf * 4 + lg) ^ (lr & 7);
            phr[hb][kf] = (const f16x8*)((const char*)&hA[hb][0][lr][0] + slot * 16);
        }
    const int slx = lg ^ (lr & 3); // x reads: pxc[tt*64], buf stride 512 units
    const f16x8* px = (const f16x8*)((const char*)&xA[0][0][lr][0] + slx * 16);
    _Float16* pw[2][4];            // h writes: [hb][r], lo at +1024 (u16)
    #pragma unroll
    for (int hb = 0; hb < 2; ++hb)
        #pragma unroll
        for (int r = 0; r < 4; ++r) {
            const int row = lg * 4 + r;
            const int k   = 16 * w + lr;
            const int kp  = (k & 7) | (((k >> 3) ^ (row & 7)) << 3);
            pw[hb][r] = &hA[hb][0][row][kp];
        }

    // ---- zero LDS (h0 = 0; x pad slots stay 0 forever) ----
    for (int i = tid; i < 2 * 2 * MB * HIDDEN; i += 256)
        ((unsigned short*)hA)[i] = 0;
    for (int i = tid; i < 2 * CS * MB * 32; i += 256)
        ((unsigned short*)xA)[i] = 0;

    float c[4]    = {0.f, 0.f, 0.f, 0.f};
    float hreg[4] = {0.f, 0.f, 0.f, 0.f};

    // ---- x chunk loader: 16 rows x 8 tt x 16 (padded) = 2048 slots ----
    float stg[8];
    auto load_chunk = [&](int ch) {
        #pragma unroll
        for (int s = 0; s < 8; ++s) {
            const int idx = tid + s * 256;   // 0..2047
            const int i   = idx & 15;
            const int tt  = (idx >> 4) & 7;
            const int r   = idx >> 7;        // 0..15
            float v = 0.0f;
            if (i < INPUT)
                v = x[(size_t)(row0 + r) * (T_STEPS * INPUT)
                      + (size_t)(ch * CS + tt) * INPUT + i];
            stg[s] = v;
        }
    };
    auto store_chunk = [&](int buf) {
        #pragma unroll
        for (int s = 0; s < 8; ++s) {
            const int idx = tid + s * 256;
            const int i   = idx & 15;
            const int tt  = (idx >> 4) & 7;
            const int r   = idx >> 7;
            const int kp  = (i & 7) | (((i >> 3) ^ (r & 3)) << 3);
            xA[buf][tt][r][kp] = (_Float16)stg[s];
        }
    };

    load_chunk(0);
    __syncthreads();          // zero-init visible
    store_chunk(0);
    __syncthreads();

    for (int ch = 0; ch < NCHUNK; ++ch) {
        const int cur = ch & 1;
        const f16x8* pxc = px + cur * 512;
        if (ch + 1 < NCHUNK)
            load_chunk(ch + 1);          // global loads in flight over 8 steps

        #pragma unroll
        for (int tt = 0; tt < CS; ++tt) {
            const int hb  = tt & 1;      // read parity (static after unroll)
            const int hbw = hb ^ 1;      // write parity

            // ---- LDS reads: x then h (all base+imm) ----
            const f16x8 ax0    = pxc[tt * 64];
            const f16x8 ah_hi0 = phr[hb][0][0];
            const f16x8 ah_lo0 = phr[hb][0][128];
            const f16x8 ah_hi1 = phr[hb][1][0];
            const f16x8 ah_lo1 = phr[hb][1][128];

            // ---- gate GEMM: 5 MFMAs/gate-type, single chain (bias as C-in) ----
            f32x4 acc[4];
            #pragma unroll
            for (int gt = 0; gt < 4; ++gt) {
                f32x4 a = biasv[gt];
                a = __builtin_amdgcn_mfma_f32_16x16x32_f16(ax0,    Bx[gt],    a, 0, 0, 0);
                a = __builtin_amdgcn_mfma_f32_16x16x32_f16(ah_hi0, Bh[gt][0], a, 0, 0, 0);
                a = __builtin_amdgcn_mfma_f32_16x16x32_f16(ah_lo0, Bh[gt][0], a, 0, 0, 0);
                a = __builtin_amdgcn_mfma_f32_16x16x32_f16(ah_hi1, Bh[gt][1], a, 0, 0, 0);
                a = __builtin_amdgcn_mfma_f32_16x16x32_f16(ah_lo1, Bh[gt][1], a, 0, 0, 0);
                acc[gt] = a;
            }

            // ---- cell update (exp2-direct activations); write split h ----
            #pragma unroll
            for (int r = 0; r < 4; ++r) {
                const float ig = rcp_f(1.0f + exp2_f(acc[0][r]));
                const float fg = rcp_f(1.0f + exp2_f(acc[1][r]));
                const float gg = fmaf(-2.0f, rcp_f(1.0f + exp2_f(acc[2][r])), 1.0f);
                const float og = rcp_f(1.0f + exp2_f(acc[3][r]));
                c[r] = fmaf(fg, c[r], ig * gg);
                const float tc = exp2_f((2.0f * LOG2E) * c[r]);
                const float th = fmaf(-2.0f, rcp_f(1.0f + tc), 1.0f);
                const float h  = og * th;
                hreg[r] = h;
                const _Float16 hi = (_Float16)h;
                const _Float16 lo = (_Float16)(h - (float)hi);
                pw[hbw][r][0]    = hi;
                pw[hbw][r][1024] = lo;     // split stride = MB*HIDDEN u16
            }

            // fold chunk staging into the last step (no extra barrier)
            if (tt == CS - 1 && ch + 1 < NCHUNK)
                store_chunk(1 - cur);

            __syncthreads();
        }
    }

    // ---- epilogue: out[row] = sigmoid(h_T . W_fc + b_fc) ----
    #pragma unroll
    for (int r = 0; r < 4; ++r)
        hf[lg * 4 + r][16 * w + lr] = hreg[r];
    __syncthreads();
    if (tid < MB) {
        float a = b_fc[0];
        #pragma unroll
        for (int j = 0; j < HIDDEN; ++j)
            a = fmaf(hf[tid][j], W_fc[j], a);
        out[row0 + tid] = sigmoid_f(a);
    }
}

extern "C" void kernel_launch(void* const* d_in, const int* in_sizes, int n_in,
                              void* d_out, int out_size, void* d_ws, size_t ws_size,
                              hipStream_t stream) {
    const float* x    = (const float*)d_in[0];
    const float* W_ih = (const float*)d_in[1];
    const float* W_hh = (const float*)d_in[2];
    const float* b_ih = (const float*)d_in[3];
    const float* b_hh = (const float*)d_in[4];
    const float* W_fc = (const float*)d_in[5];
    const float* b_fc = (const float*)d_in[6];
    float* out = (float*)d_out;

    const int B = 4096;
    dim3 grid(B / MB), block(256);
    lstm_mfma_kernel<<<grid, block, 0, stream>>>(x, W_ih, W_hh, b_ih, b_hh,
                                                 W_fc, b_fc, out);
}

// Round 12
// 225.006 us; speedup vs baseline: 4.1784x; 1.2285x over previous
//
#include <hip/hip_runtime.h>

#define T_STEPS 512
#define INPUT   13
#define HIDDEN  64
#define MB      16    // full MFMA M-tile, grid 256 = 1 block/CU
#define CS      8     // timesteps per x-chunk
#define NCHUNK  (T_STEPS / CS)
#define LOG2E   1.44269504088896f

typedef __attribute__((ext_vector_type(8))) _Float16 f16x8;  // MFMA A/B frag (4 VGPR)
typedef __attribute__((ext_vector_type(4)))  float   f32x4;  // MFMA C/D frag

__device__ __forceinline__ float exp2_f(float x) { return __builtin_amdgcn_exp2f(x); }
__device__ __forceinline__ float rcp_f(float x)  { return __builtin_amdgcn_rcpf(x); }
__device__ __forceinline__ float sigmoid_f(float x) {           // epilogue only
    return rcp_f(1.0f + exp2_f(-LOG2E * x));
}

// R11 post-mortem (wall 1295 cyc/step/SIMD, ledger closed): MFMA pipe 320,
// VALU 650 (trans 40/lane @ quarter-rate = 320 + regular 250), latency 330.
// R12 cuts, both 1:1 issue savings:
//  - single-f16 h (drop lo plane): 20 -> 12 MFMAs, -12 cvt, -4 writes.
//    absmax evidence: pinned at 2^-8 across 3 precision schemes -> split
//    terms aren't the binding error; expected growth <= ~2x.
//  - combined-rcp gate algebra: i*g = (B-1)*rcp((1+A)(1+B)),
//    o*tanh(c) = (T-1)*rcp((1+O)(1+T)), f*c = c*rcp(1+F):
//    8 trans/cell instead of 10 (-64 cyc/step).
__global__ __launch_bounds__(256, 1)
void lstm_mfma_kernel(const float* __restrict__ x,
                      const float* __restrict__ W_ih,
                      const float* __restrict__ W_hh,
                      const float* __restrict__ b_ih,
                      const float* __restrict__ b_hh,
                      const float* __restrict__ W_fc,
                      const float* __restrict__ b_fc,
                      float* __restrict__ out)
{
    // h frags: [buf][row][k] f16, slot ^= row&7 swizzle (slot = 16B)
    __shared__ _Float16 hA[2][MB][HIDDEN];         // 4 KB
    // x frags: [buf][tt][row][k(32, zero-padded)] f16, slot ^= row&3
    __shared__ _Float16 xA[2][CS][MB][32];         // 16 KB
    __shared__ float hf[MB][HIDDEN];               // epilogue, 4 KB

    const int tid = threadIdx.x;
    const int w   = tid >> 6;      // wave 0..3
    const int l   = tid & 63;
    const int lr  = l & 15;        // MFMA row/col index
    const int lg  = l >> 4;        // MFMA k-group
    const int row0 = blockIdx.x * MB;

    // ---- resident weight B-frags (f16, activation-scale folded) ----
    // sigma gates (i,f,o): scl = -log2e -> exp2(acc) = e^{-pre}
    // g gate:              scl = 2log2e -> exp2(acc) = e^{2 pre}
    f16x8 Bh[4][2], Bx[4];
    f32x4 biasv[4];
    #pragma unroll
    for (int gt = 0; gt < 4; ++gt) {
        const int gate  = gt * 64 + 16 * w + lr;
        const float scl = (gt == 2) ? (2.0f * LOG2E) : (-LOG2E);
        const float b   = scl * (b_ih[gate] + b_hh[gate]);
        biasv[gt] = (f32x4){b, b, b, b};
        #pragma unroll
        for (int kf = 0; kf < 2; ++kf)
            #pragma unroll
            for (int j = 0; j < 8; ++j)
                Bh[gt][kf][j] = (_Float16)(scl * W_hh[gate * HIDDEN + kf * 32 + lg * 8 + j]);
        #pragma unroll
        for (int j = 0; j < 8; ++j) {
            const int k = lg * 8 + j;
            Bx[gt][j] = (_Float16)((k < INPUT) ? scl * W_ih[gate * INPUT + k] : 0.0f);
        }
    }

    // ---- precomputed LDS pointers ----
    const f16x8* phr[2][2];        // h reads: [hb][kf] (f16x8 units)
    #pragma unroll
    for (int hb = 0; hb < 2; ++hb)
        #pragma unroll
        for (int kf = 0; kf < 2; ++kf) {
            const int slot = (kf * 4 + lg) ^ (lr & 7);
            phr[hb][kf] = (const f16x8*)((const char*)&hA[hb][lr][0] + slot * 16);
        }
    const int slx = lg ^ (lr & 3); // x reads: pxc[tt*64], buf stride 512 units
    const f16x8* px = (const f16x8*)((const char*)&xA[0][0][lr][0] + slx * 16);
    _Float16* pw[2][4];            // h writes: [hb][r]
    #pragma unroll
    for (int hb = 0; hb < 2; ++hb)
        #pragma unroll
        for (int r = 0; r < 4; ++r) {
            const int row = lg * 4 + r;
            const int k   = 16 * w + lr;
            const int kp  = (k & 7) | (((k >> 3) ^ (row & 7)) << 3);
            pw[hb][r] = &hA[hb][row][kp];
        }

    // ---- zero LDS (h0 = 0; x pad slots stay 0 forever) ----
    for (int i = tid; i < 2 * MB * HIDDEN; i += 256)
        ((unsigned short*)hA)[i] = 0;
    for (int i = tid; i < 2 * CS * MB * 32; i += 256)
        ((unsigned short*)xA)[i] = 0;

    float c[4]    = {0.f, 0.f, 0.f, 0.f};
    float hreg[4] = {0.f, 0.f, 0.f, 0.f};

    // ---- x chunk loader: 16 rows x 8 tt x 16 (padded) = 2048 slots ----
    float stg[8];
    auto load_chunk = [&](int ch) {
        #pragma unroll
        for (int s = 0; s < 8; ++s) {
            const int idx = tid + s * 256;   // 0..2047
            const int i   = idx & 15;
            const int tt  = (idx >> 4) & 7;
            const int r   = idx >> 7;        // 0..15
            float v = 0.0f;
            if (i < INPUT)
                v = x[(size_t)(row0 + r) * (T_STEPS * INPUT)
                      + (size_t)(ch * CS + tt) * INPUT + i];
            stg[s] = v;
        }
    };
    auto store_chunk = [&](int buf) {
        #pragma unroll
        for (int s = 0; s < 8; ++s) {
            const int idx = tid + s * 256;
            const int i   = idx & 15;
            const int tt  = (idx >> 4) & 7;
            const int r   = idx >> 7;
            const int kp  = (i & 7) | (((i >> 3) ^ (r & 3)) << 3);
            xA[buf][tt][r][kp] = (_Float16)stg[s];
        }
    };

    load_chunk(0);
    __syncthreads();          // zero-init visible
    store_chunk(0);
    __syncthreads();

    for (int ch = 0; ch < NCHUNK; ++ch) {
        const int cur = ch & 1;
        const f16x8* pxc = px + cur * 512;
        if (ch + 1 < NCHUNK)
            load_chunk(ch + 1);          // global loads in flight over 8 steps

        #pragma unroll
        for (int tt = 0; tt < CS; ++tt) {
            const int hb  = tt & 1;      // read parity (static after unroll)
            const int hbw = hb ^ 1;      // write parity

            // ---- LDS reads: x then h (all base+imm) ----
            const f16x8 ax0 = pxc[tt * 64];
            const f16x8 ah0 = phr[hb][0][0];
            const f16x8 ah1 = phr[hb][1][0];

            // ---- gate GEMM: 3 MFMAs/gate-type, single chain (bias as C-in) ----
            f32x4 acc[4];
            #pragma unroll
            for (int gt = 0; gt < 4; ++gt) {
                f32x4 a = biasv[gt];
                a = __builtin_amdgcn_mfma_f32_16x16x32_f16(ax0, Bx[gt],    a, 0, 0, 0);
                a = __builtin_amdgcn_mfma_f32_16x16x32_f16(ah0, Bh[gt][0], a, 0, 0, 0);
                a = __builtin_amdgcn_mfma_f32_16x16x32_f16(ah1, Bh[gt][1], a, 0, 0, 0);
                acc[gt] = a;
            }

            // ---- cell update: combined-rcp algebra (8 trans/cell) ----
            #pragma unroll
            for (int r = 0; r < 4; ++r) {
                const float A = exp2_f(acc[0][r]);   // e^{-pre_i}
                const float F = exp2_f(acc[1][r]);   // e^{-pre_f}
                const float B = exp2_f(acc[2][r]);   // e^{+2 pre_g}
                const float O = exp2_f(acc[3][r]);   // e^{-pre_o}
                const float ig = (B - 1.0f) * rcp_f((1.0f + A) * (1.0f + B));
                const float cn = fmaf(c[r], rcp_f(1.0f + F), ig);
                c[r] = cn;
                const float T = exp2_f((2.0f * LOG2E) * cn);   // e^{2c}
                const float h = (T - 1.0f) * rcp_f((1.0f + O) * (1.0f + T));
                hreg[r] = h;
                pw[hbw][r][0] = (_Float16)h;
            }

            // fold chunk staging into the last step (no extra barrier)
            if (tt == CS - 1 && ch + 1 < NCHUNK)
                store_chunk(1 - cur);

            __syncthreads();
        }
    }

    // ---- epilogue: out[row] = sigmoid(h_T . W_fc + b_fc) ----
    #pragma unroll
    for (int r = 0; r < 4; ++r)
        hf[lg * 4 + r][16 * w + lr] = hreg[r];
    __syncthreads();
    if (tid < MB) {
        float a = b_fc[0];
        #pragma unroll
        for (int j = 0; j < HIDDEN; ++j)
            a = fmaf(hf[tid][j], W_fc[j], a);
        out[row0 + tid] = sigmoid_f(a);
    }
}

extern "C" void kernel_launch(void* const* d_in, const int* in_sizes, int n_in,
                              void* d_out, int out_size, void* d_ws, size_t ws_size,
                              hipStream_t stream) {
    const float* x    = (const float*)d_in[0];
    const float* W_ih = (const float*)d_in[1];
    const float* W_hh = (const float*)d_in[2];
    const float* b_ih = (const float*)d_in[3];
    const float* b_hh = (const float*)d_in[4];
    const float* W_fc = (const float*)d_in[5];
    const float* b_fc = (const float*)d_in[6];
    float* out = (float*)d_out;

    const int B = 4096;
    dim3 grid(B / MB), block(256);
    lstm_mfma_kernel<<<grid, block, 0, stream>>>(x, W_ih, W_hh, b_ih, b_hh,
                                                 W_fc, b_fc, out);
}